// Round 5
// baseline (869.620 us; speedup 1.0000x reference)
//
#include <hip/hip_runtime.h>
#include <stdint.h>

#define H 4096

typedef float v4f __attribute__((ext_vector_type(4)));
typedef long long i64;
typedef long long v2l __attribute__((ext_vector_type(2)));

__device__ __forceinline__ void gload16(const uint8_t* g, uint8_t* l) {
  __builtin_amdgcn_global_load_lds(
      (const __attribute__((address_space(1))) uint8_t*)g,
      (__attribute__((address_space(3))) uint8_t*)l, 16, 0, 0);
}

// permuted byte position within a 128-B k-block: orig b = ks*32 + q*8 + j
// stored at q*32 + ks*8 + j
__device__ __forceinline__ int permpos(int kg) {
  const int kb = kg >> 7, b = kg & 127;
  const int ks = b >> 5, q = (b >> 3) & 3, j = b & 7;
  return kb * 128 + q * 32 + ks * 8 + j;
}

// ---- weights: fp32 [k][n] -> fp8 transposed+permuted [n][perm(k)] ----
__global__ __launch_bounds__(256) void conv_w_kernel(
    const float* __restrict__ w0, const float* __restrict__ w1,
    const float* __restrict__ w2, uint8_t* __restrict__ o0,
    uint8_t* __restrict__ o1, uint8_t* __restrict__ o2) {
  const float* w = (blockIdx.z == 0) ? w0 : (blockIdx.z == 1 ? w1 : w2);
  uint8_t* o = (blockIdx.z == 0) ? o0 : (blockIdx.z == 1 ? o1 : o2);
  __shared__ uint8_t t[64][68];
  const int tid = threadIdx.x;
  const int k0 = blockIdx.y * 64, n0 = blockIdx.x * 64;
  const int rr = tid >> 4, cc = (tid & 15) * 4;
#pragma unroll
  for (int j = 0; j < 4; ++j) {
    const int r = rr + j * 16;
    v4f f = *(const v4f*)(w + (size_t)(k0 + r) * H + n0 + cc);
    unsigned p = __builtin_amdgcn_cvt_pk_fp8_f32(f.x, f.y, 0, false);
    p = __builtin_amdgcn_cvt_pk_fp8_f32(f.z, f.w, p, true);
    t[cc + 0][r] = p & 0xff;
    t[cc + 1][r] = (p >> 8) & 0xff;
    t[cc + 2][r] = (p >> 16) & 0xff;
    t[cc + 3][r] = p >> 24;
  }
  __syncthreads();
#pragma unroll
  for (int j = 0; j < 4; ++j) {
    const int n = rr + j * 16;
    unsigned p = (unsigned)t[n][cc] | ((unsigned)t[n][cc + 1] << 8) |
                 ((unsigned)t[n][cc + 2] << 16) |
                 ((unsigned)t[n][cc + 3] << 24);
    *(unsigned*)(o + (size_t)(n0 + n) * H + permpos(k0 + cc)) = p;
  }
}

// ---- row kernel: (optional relu) + rmsnorm + group-128 fp8 quant ----
__global__ __launch_bounds__(256) void quant_kernel(
    const float* in, const float* __restrict__ nw, uint8_t* __restrict__ q,
    float* __restrict__ sxT, const int relu) {
  const int row = blockIdx.x, tid = threadIdx.x;
  const v4f* rp = (const v4f*)(in + (size_t)row * H);
  v4f v[4];
  float ss = 0.f;
#pragma unroll
  for (int j = 0; j < 4; ++j) {
    v4f x = rp[j * 256 + tid];
    if (relu) {
      x.x = fmaxf(x.x, 0.f); x.y = fmaxf(x.y, 0.f);
      x.z = fmaxf(x.z, 0.f); x.w = fmaxf(x.w, 0.f);
    }
    v[j] = x;
    ss += x.x * x.x + x.y * x.y + x.z * x.z + x.w * x.w;
  }
#pragma unroll
  for (int o = 32; o > 0; o >>= 1) ss += __shfl_down(ss, o);
  __shared__ float red[4];
  if ((tid & 63) == 0) red[tid >> 6] = ss;
  __syncthreads();
  ss = red[0] + red[1] + red[2] + red[3];
  const float rinv = 1.f / sqrtf(ss * (1.f / H) + 1e-6f);
#pragma unroll
  for (int j = 0; j < 4; ++j) {
    v4f nv = ((const v4f*)nw)[j * 256 + tid];
    v4f y;
    y.x = v[j].x * rinv * nv.x;
    y.y = v[j].y * rinv * nv.y;
    y.z = v[j].z * rinv * nv.z;
    y.w = v[j].w * rinv * nv.w;
    float am = fmaxf(fmaxf(fabsf(y.x), fabsf(y.y)), fmaxf(fabsf(y.z), fabsf(y.w)));
#pragma unroll
    for (int o = 16; o > 0; o >>= 1) am = fmaxf(am, __shfl_xor(am, o, 32));
    const float s = fmaxf(am, 1e-12f) / 448.f;
    unsigned p = __builtin_amdgcn_cvt_pk_fp8_f32(y.x / s, y.y / s, 0, false);
    p = __builtin_amdgcn_cvt_pk_fp8_f32(y.z / s, y.w / s, p, true);
    const int col = (j * 256 + tid) * 4;
    *(unsigned*)(q + (size_t)row * H + permpos(col)) = p;
    if ((tid & 31) == 0)
      sxT[(size_t)(j * 8 + (tid >> 5)) * 4096 + row] = s;
  }
}

// ---- final rmsnorm, in-place on d_out ----
__global__ __launch_bounds__(256) void norm_kernel(float* io,
                                                   const float* __restrict__ nw) {
  const int row = blockIdx.x, tid = threadIdx.x;
  v4f* rp = (v4f*)(io + (size_t)row * H);
  v4f v[4];
  float ss = 0.f;
#pragma unroll
  for (int j = 0; j < 4; ++j) {
    v4f x = rp[j * 256 + tid];
    v[j] = x;
    ss += x.x * x.x + x.y * x.y + x.z * x.z + x.w * x.w;
  }
#pragma unroll
  for (int o = 32; o > 0; o >>= 1) ss += __shfl_down(ss, o);
  __shared__ float red[4];
  if ((tid & 63) == 0) red[tid >> 6] = ss;
  __syncthreads();
  ss = red[0] + red[1] + red[2] + red[3];
  const float rinv = 1.f / sqrtf(ss * (1.f / H) + 1e-6f);
#pragma unroll
  for (int j = 0; j < 4; ++j) {
    v4f nv = ((const v4f*)nw)[j * 256 + tid];
    v4f y;
    y.x = v[j].x * rinv * nv.x;
    y.y = v[j].y * rinv * nv.y;
    y.z = v[j].z * rinv * nv.z;
    y.w = v[j].w * rinv * nv.w;
    rp[j * 256 + tid] = y;
  }
}

// ---- block-scaled fp8 GEMM, 256x256 tile, 8 waves, DEEP pipeline ----
// BK=64 K-steps (64 of them), 4-buffer ring, 3 steps prefetched ahead.
// Every step: uniform 5-gload bundle (2A+2B+1scale), counted s_waitcnt
// vmcnt(15)=3 bundles -- NEVER a full drain in the main loop. Tail 3 steps
// peel with vmcnt(10/5/0).
// Scale col c (read at steps 2c,2c+1; slot c&3) is staged by bundles
// j=2c-2,2c-1 (kbs_=(j+2)>>1), i.e. at steps 2c-5,2c-4: WAR-safe (col c-4's
// last read is step 2c-7, and staging issues after that step's end barrier)
// and landing-guaranteed (bundle j is covered by the vmcnt wait at step j
// <= 2c-1 < first read).  [R4 bug: (j+6)>>1 skipped cols 1-2 and clobbered
// live cols 4 steps early -> absmax 3.9e-2.]
__global__ __launch_bounds__(512, 2) void gemm_kernel(
    const uint8_t* __restrict__ qa,   // [M][perm(K)] fp8 activations
    const float* __restrict__ sxT,    // [32][M] act scales, transposed
    const uint8_t* __restrict__ wt,   // [N][perm(K)] fp8 weight
    const float* __restrict__ ws,     // [32][32] weight scales [kb][nb]
    const float* resid, float* outp, const int relu) {
  __shared__ __attribute__((aligned(16))) uint8_t sA[4][16384];
  __shared__ __attribute__((aligned(16))) uint8_t sB[4][16384];
  __shared__ __attribute__((aligned(16))) float scb[4][256];  // act scales ring
  __shared__ float ws_s[64];                                  // [kb][2 n-halves]

  const int tid = threadIdx.x;

  // bijective XCD swizzle: 256 blocks, 8 XCDs
  const int lid = blockIdx.y * 16 + blockIdx.x;
  const int nl = (lid & 7) * 32 + (lid >> 3);
  const int m0 = (nl >> 4) * 256, n0 = (nl & 15) * 256;

  const int wv = tid >> 6, lane = tid & 63;
  const int quad = lane >> 4, l16 = lane & 15;
  const int wm = wv >> 2, wn = wv & 3;  // 2x4 wave grid, wave tile 128x64
  const int whalf = wn >> 1;

  if (tid < 64) ws_s[tid] = ws[(tid >> 1) * 32 + (n0 >> 7) + (tid & 1)];

  // staging lane constants: lane l covers (row = wv*32 + i*16 + (l>>2),
  // slot s=(l&3)) holding global chunk q = s ^ ((row>>1)&3) = (l&3)^((l>>3)&3)
  const int lr = lane >> 2;
  const int qch = (lane & 3) ^ ((lane >> 3) & 3);
  const uint8_t* pAg = qa + (size_t)(m0 + wv * 32 + lr) * H + qch * 32;
  const uint8_t* pBg = wt + (size_t)(n0 + wv * 32 + lr) * H + qch * 32;
  const uint8_t* pSg = (const uint8_t*)sxT + (size_t)m0 * 4 + lane * 16;

  // bundle(j): stage K-step j (kb=j>>1, half par=j&1) + scale col (j+2)>>1
  auto stage = [&](int j) {
    const int kb_ = j >> 1, par_ = j & 1, bi_ = j & 3;
    const size_t ko_ = (size_t)kb_ * 128 + par_ * 16;
    gload16(pAg + ko_, sA[bi_] + wv * 2048);
    gload16(pAg + (size_t)16 * H + ko_, sA[bi_] + wv * 2048 + 1024);
    gload16(pBg + ko_, sB[bi_] + wv * 2048);
    gload16(pBg + (size_t)16 * H + ko_, sB[bi_] + wv * 2048 + 1024);
    int kbs_ = (j + 2) >> 1;            // scale col: in [2c-5,2c-4] window
    if (kbs_ > 31) kbs_ = 31;           // clamp (idempotent re-stage)
    gload16(pSg + (size_t)kbs_ * 16384, (uint8_t*)scb[kbs_ & 3]);
  };

  // fragment read offsets: slot s = quad ^ ((row>>1)&3), row bits1-2 = l16
  const int swq = (quad ^ ((l16 >> 1) & 3)) << 4;
  const int aoff = (wm * 128 + l16) * 64 + swq;  // + tr*1024
  const int boff = (wn * 64 + l16) * 64 + swq;   // + tc*1024
  const int soff = wm * 512 + quad * 16;         // + tr*64 (bytes)

  const v4f zf = {0.f, 0.f, 0.f, 0.f};
  v4f acc[8][4];
#pragma unroll
  for (int i = 0; i < 8; ++i)
#pragma unroll
    for (int j = 0; j < 4; ++j) acc[i][j] = zf;

  // prologue: scale col 0 + steps 0..2 (stage cols 1,1,2), then full drain
  gload16(pSg, (uint8_t*)scb[0]);
  stage(0);
  stage(1);
  stage(2);
  __syncthreads();  // drains vmcnt+lgkm; ws_s visible

  auto dostep = [&](int ks) {
    __builtin_amdgcn_s_barrier();        // all waves' vmcnt wait done -> buf ready
    __builtin_amdgcn_sched_barrier(0);   // don't hoist ds_reads above barrier
    const uint8_t* Ab = sA[ks & 3];
    const uint8_t* Bb = sB[ks & 3];
    const uint8_t* Sb = (const uint8_t*)scb[(ks >> 1) & 3];
    const float wsk = ws_s[(ks >> 1) * 2 + whalf];
    v2l b[4], a[8];
    v4f s4[8];
#pragma unroll
    for (int tc = 0; tc < 4; ++tc) b[tc] = *(const v2l*)(Bb + boff + tc * 1024);
#pragma unroll
    for (int tr = 0; tr < 8; ++tr) a[tr] = *(const v2l*)(Ab + aoff + tr * 1024);
#pragma unroll
    for (int tr = 0; tr < 8; ++tr) s4[tr] = *(const v4f*)(Sb + soff + tr * 64);
    asm volatile("s_waitcnt lgkmcnt(0)" ::: "memory");
    __builtin_amdgcn_sched_barrier(0);
    __builtin_amdgcn_s_setprio(1);
#pragma unroll
    for (int tr = 0; tr < 8; ++tr) {
      const v4f sv = s4[tr] * wsk;
#pragma unroll
      for (int tc = 0; tc < 4; ++tc) {
        v4f pr = __builtin_amdgcn_mfma_f32_16x16x32_fp8_fp8(a[tr].x, b[tc].x, zf, 0, 0, 0);
        pr = __builtin_amdgcn_mfma_f32_16x16x32_fp8_fp8(a[tr].y, b[tc].y, pr, 0, 0, 0);
        acc[tr][tc] += pr * sv;
      }
    }
    __builtin_amdgcn_s_setprio(0);
    __builtin_amdgcn_s_barrier();        // reads done before next overwrite issue
  };

  for (int ks = 0; ks < 61; ++ks) {
    stage(ks + 3);
    asm volatile("s_waitcnt vmcnt(15)" ::: "memory");  // 3 bundles in flight
    dostep(ks);
  }
  asm volatile("s_waitcnt vmcnt(10)" ::: "memory");
  dostep(61);
  asm volatile("s_waitcnt vmcnt(5)" ::: "memory");
  dostep(62);
  asm volatile("s_waitcnt vmcnt(0)" ::: "memory");
  dostep(63);

  // epilogue: add residual (relu(x) for layer 0)
  const int mB = m0 + wm * 128 + quad * 4;
  const int nB = n0 + wn * 64 + l16;
#pragma unroll
  for (int tr = 0; tr < 8; ++tr) {
#pragma unroll
    for (int r = 0; r < 4; ++r) {
      const size_t rowOff = (size_t)(mB + tr * 16 + r) * H;
#pragma unroll
      for (int tc = 0; tc < 4; ++tc) {
        const size_t idx = rowOff + nB + tc * 16;
        float rv = resid[idx];
        if (relu) rv = fmaxf(rv, 0.f);
        outp[idx] = acc[tr][tc][r] + rv;
      }
    }
  }
}

extern "C" void kernel_launch(void* const* d_in, const int* in_sizes, int n_in,
                              void* d_out, int out_size, void* d_ws, size_t ws_size,
                              hipStream_t stream) {
  const float* x   = (const float*)d_in[0];
  const float* w0  = (const float*)d_in[1];
  const float* ws0 = (const float*)d_in[2];
  const float* w1  = (const float*)d_in[3];
  const float* ws1 = (const float*)d_in[4];
  const float* w2  = (const float*)d_in[5];
  const float* ws2 = (const float*)d_in[6];
  const float* nw0 = (const float*)d_in[7];
  const float* nw1 = (const float*)d_in[8];
  const float* nw2 = (const float*)d_in[9];
  const float* nw3 = (const float*)d_in[10];
  float* R = (float*)d_out;  // residual lives in d_out (in-place)

  uint8_t* base = (uint8_t*)d_ws;
  uint8_t* wq0 = base;
  uint8_t* wq1 = base + ((size_t)16 << 20);
  uint8_t* wq2 = base + ((size_t)32 << 20);
  uint8_t* qa  = base + ((size_t)48 << 20);
  float* sa    = (float*)(base + ((size_t)64 << 20));  // sxT[32][4096]

  conv_w_kernel<<<dim3(64, 64, 3), 256, 0, stream>>>(w0, w1, w2, wq0, wq1, wq2);

  quant_kernel<<<4096, 256, 0, stream>>>(x, nw0, qa, sa, 1);
  gemm_kernel<<<dim3(16, 16), 512, 0, stream>>>(qa, sa, wq0, ws0, x, R, 1);

  quant_kernel<<<4096, 256, 0, stream>>>(R, nw1, qa, sa, 0);
  gemm_kernel<<<dim3(16, 16), 512, 0, stream>>>(qa, sa, wq1, ws1, R, R, 0);

  quant_kernel<<<4096, 256, 0, stream>>>(R, nw2, qa, sa, 0);
  gemm_kernel<<<dim3(16, 16), 512, 0, stream>>>(qa, sa, wq2, ws2, R, R, 0);

  norm_kernel<<<4096, 256, 0, stream>>>(R, nw3);
}

// Round 6
// 685.989 us; speedup vs baseline: 1.2677x; 1.2677x over previous
//
#include <hip/hip_runtime.h>
#include <stdint.h>

#define H 4096

typedef float v4f __attribute__((ext_vector_type(4)));
typedef long long i64;
typedef long long v2l __attribute__((ext_vector_type(2)));

__device__ __forceinline__ void gload16(const uint8_t* g, uint8_t* l) {
  __builtin_amdgcn_global_load_lds(
      (const __attribute__((address_space(1))) uint8_t*)g,
      (__attribute__((address_space(3))) uint8_t*)l, 16, 0, 0);
}

// permuted byte position within a 128-B k-block: orig b = ks*32 + q*8 + j
// stored at q*32 + ks*8 + j  (so each lane's (q, ks) and (q, ks+1) fragments
// are 16 contiguous bytes -> ds_read_b128 in the GEMM)
__device__ __forceinline__ int permpos(int kg) {
  const int kb = kg >> 7, b = kg & 127;
  const int ks = b >> 5, q = (b >> 3) & 3, j = b & 7;
  return kb * 128 + q * 32 + ks * 8 + j;
}

// ---- weights: fp32 [k][n] -> fp8 transposed+permuted [n][perm(k)] ----
// Tile 128k x 64n. fp8 transpose via LDS [n][k], then emit the permuted
// layout as COALESCED 16B/lane stores: output slot o16 = c&7 covers bytes
// [32q+16h, +16) (q=o16>>1, h=o16&1) <- LDS k-bytes {64h+q*8..+7} then
// {64h+32+q*8..+7} (algebraic inverse of permpos; 8 lanes = one full
// contiguous 128B block of one n-row).  [Old version: per-lane scattered
// 4B stores -> write-combine/sector amplification.]
__global__ __launch_bounds__(256) void conv_w_kernel(
    const float* __restrict__ w0, const float* __restrict__ w1,
    const float* __restrict__ w2, uint8_t* __restrict__ o0,
    uint8_t* __restrict__ o1, uint8_t* __restrict__ o2) {
  const float* w = (blockIdx.z == 0) ? w0 : (blockIdx.z == 1 ? w1 : w2);
  uint8_t* o = (blockIdx.z == 0) ? o0 : (blockIdx.z == 1 ? o1 : o2);
  __shared__ uint8_t t[64][136];  // [n][k], pad 136 -> 8B-aligned rows
  const int tid = threadIdx.x;
  const int k0 = blockIdx.y * 128, n0 = blockIdx.x * 64;
  const int rr = tid >> 4, cc = (tid & 15) * 4;
#pragma unroll
  for (int j = 0; j < 8; ++j) {
    const int r = rr + j * 16;
    v4f f = *(const v4f*)(w + (size_t)(k0 + r) * H + n0 + cc);
    unsigned p = __builtin_amdgcn_cvt_pk_fp8_f32(f.x, f.y, 0, false);
    p = __builtin_amdgcn_cvt_pk_fp8_f32(f.z, f.w, p, true);
    t[cc + 0][r] = p & 0xff;
    t[cc + 1][r] = (p >> 8) & 0xff;
    t[cc + 2][r] = (p >> 16) & 0xff;
    t[cc + 3][r] = p >> 24;
  }
  __syncthreads();
#pragma unroll
  for (int i = 0; i < 2; ++i) {
    const int c = i * 256 + tid;          // lanes 0..63 -> 8 full rows/instr
    const int n = c >> 3, o16 = c & 7, q = o16 >> 1, h = o16 & 1;
    long long lo = *(const long long*)&t[n][64 * h + q * 8];
    long long hi = *(const long long*)&t[n][64 * h + 32 + q * 8];
    v2l val;
    val.x = lo;
    val.y = hi;
    *(v2l*)(o + (size_t)(n0 + n) * H + k0 + o16 * 16) = val;
  }
}

// ---- row kernel: (optional relu) + rmsnorm + group-128 fp8 quant ----
// writes qa in permuted layout, scales transposed: sxT[kb][m]
__global__ __launch_bounds__(256) void quant_kernel(
    const float* in, const float* __restrict__ nw, uint8_t* __restrict__ q,
    float* __restrict__ sxT, const int relu) {
  const int row = blockIdx.x, tid = threadIdx.x;
  const v4f* rp = (const v4f*)(in + (size_t)row * H);
  v4f v[4];
  float ss = 0.f;
#pragma unroll
  for (int j = 0; j < 4; ++j) {
    v4f x = rp[j * 256 + tid];
    if (relu) {
      x.x = fmaxf(x.x, 0.f); x.y = fmaxf(x.y, 0.f);
      x.z = fmaxf(x.z, 0.f); x.w = fmaxf(x.w, 0.f);
    }
    v[j] = x;
    ss += x.x * x.x + x.y * x.y + x.z * x.z + x.w * x.w;
  }
#pragma unroll
  for (int o = 32; o > 0; o >>= 1) ss += __shfl_down(ss, o);
  __shared__ float red[4];
  if ((tid & 63) == 0) red[tid >> 6] = ss;
  __syncthreads();
  ss = red[0] + red[1] + red[2] + red[3];
  const float rinv = 1.f / sqrtf(ss * (1.f / H) + 1e-6f);
#pragma unroll
  for (int j = 0; j < 4; ++j) {
    v4f nv = ((const v4f*)nw)[j * 256 + tid];
    v4f y;
    y.x = v[j].x * rinv * nv.x;
    y.y = v[j].y * rinv * nv.y;
    y.z = v[j].z * rinv * nv.z;
    y.w = v[j].w * rinv * nv.w;
    float am = fmaxf(fmaxf(fabsf(y.x), fabsf(y.y)), fmaxf(fabsf(y.z), fabsf(y.w)));
#pragma unroll
    for (int o = 16; o > 0; o >>= 1) am = fmaxf(am, __shfl_xor(am, o, 32));
    const float s = fmaxf(am, 1e-12f) / 448.f;  // true div: match ref bit-exact
    unsigned p = __builtin_amdgcn_cvt_pk_fp8_f32(y.x / s, y.y / s, 0, false);
    p = __builtin_amdgcn_cvt_pk_fp8_f32(y.z / s, y.w / s, p, true);
    const int col = (j * 256 + tid) * 4;
    *(unsigned*)(q + (size_t)row * H + permpos(col)) = p;
    if ((tid & 31) == 0)
      sxT[(size_t)(j * 8 + (tid >> 5)) * 4096 + row] = s;
  }
}

// ---- final rmsnorm, in-place on d_out ----
__global__ __launch_bounds__(256) void norm_kernel(float* io,
                                                   const float* __restrict__ nw) {
  const int row = blockIdx.x, tid = threadIdx.x;
  v4f* rp = (v4f*)(io + (size_t)row * H);
  v4f v[4];
  float ss = 0.f;
#pragma unroll
  for (int j = 0; j < 4; ++j) {
    v4f x = rp[j * 256 + tid];
    v[j] = x;
    ss += x.x * x.x + x.y * x.y + x.z * x.z + x.w * x.w;
  }
#pragma unroll
  for (int o = 32; o > 0; o >>= 1) ss += __shfl_down(ss, o);
  __shared__ float red[4];
  if ((tid & 63) == 0) red[tid >> 6] = ss;
  __syncthreads();
  ss = red[0] + red[1] + red[2] + red[3];
  const float rinv = 1.f / sqrtf(ss * (1.f / H) + 1e-6f);
#pragma unroll
  for (int j = 0; j < 4; ++j) {
    v4f nv = ((const v4f*)nw)[j * 256 + tid];
    v4f y;
    y.x = v[j].x * rinv * nv.x;
    y.y = v[j].y * rinv * nv.y;
    y.z = v[j].z * rinv * nv.z;
    y.w = v[j].w * rinv * nv.w;
    rp[j * 256 + tid] = y;
  }
}

// ---- block-scaled fp8 GEMM on permuted tiles (R0 structure, verbatim) ----
// 128^2 tile, 4 waves, 4 blocks/CU: cross-block overlap hides staging
// (m114 mechanism). Measured 134.6 us, MfmaUtil 42%. The 8-wave 256^2
// lock-step variants (R1/R3/R5) all regressed: 160/184/194 us.
__global__ __launch_bounds__(256, 4) void gemm_kernel(
    const uint8_t* __restrict__ qa,   // [M][perm(K)] fp8 activations
    const float* __restrict__ sxT,    // [32][M] act scales, transposed
    const uint8_t* __restrict__ wt,   // [N][perm(K)] fp8 weight
    const float* __restrict__ ws,     // [32][32] weight scales [kb][nb]
    const float* resid, float* outp, const int relu) {
  __shared__ __attribute__((aligned(16))) uint8_t sA[16384];
  __shared__ __attribute__((aligned(16))) uint8_t sB[16384];
  __shared__ __attribute__((aligned(16))) float scb[128];  // this kb's act scales
  __shared__ float ws_s[32];

  const int tid = threadIdx.x;
  const int n0 = blockIdx.x * 128, m0 = blockIdx.y * 128;
  if (tid < 32) ws_s[tid] = ws[tid * 32 + blockIdx.x];

  const int wv = tid >> 6, lane = tid & 63;
  const int quad = lane >> 4, l16 = lane & 15;
  const int wm = wv >> 1, wn = wv & 1;

  // staging: xor-swizzle the GLOBAL chunk (LDS side is fixed lane*16)
  const int swc = (tid & 7) ^ ((tid >> 3) & 7);
  const uint8_t* gA = qa + (size_t)(m0 + (tid >> 3)) * H + swc * 16;
  const uint8_t* gB = wt + (size_t)(n0 + (tid >> 3)) * H + swc * 16;
  const uint8_t* gS = (const uint8_t*)sxT + (size_t)m0 * 4 + lane * 16;
  uint8_t* lA = sA + wv * 1024;
  uint8_t* lB = sB + wv * 1024;

  // fragment LDS chunk offsets: global chunk (quad*2+ksp) xor-swizzled by row
  int offp[2];
#pragma unroll
  for (int ksp = 0; ksp < 2; ++ksp)
    offp[ksp] = (((quad * 2 + ksp) ^ (l16 & 7)) << 4);
  const int arow = (wm * 64 + l16) * 128;
  const int brow = (wn * 64 + l16) * 128;
  const int scoff = wm * 64 + quad * 4;

  const v4f zf = {0.f, 0.f, 0.f, 0.f};
  v4f acc[4][4];
#pragma unroll
  for (int i = 0; i < 4; ++i)
#pragma unroll
    for (int j = 0; j < 4; ++j) acc[i][j] = zf;

  for (int kb = 0; kb < 32; ++kb) {
#pragma unroll
    for (int i = 0; i < 4; ++i) {
      gload16(gA + (size_t)i * (32 * H), lA + i * 4096);
      gload16(gB + (size_t)i * (32 * H), lB + i * 4096);
    }
    if (wv == 0 && lane < 32) gload16(gS + (size_t)kb * 16384, (uint8_t*)scb);
    gA += 128;
    gB += 128;
    __syncthreads();

    const float wsk = ws_s[kb];
    v2l bf[4][2];
#pragma unroll
    for (int tc = 0; tc < 4; ++tc)
#pragma unroll
      for (int ksp = 0; ksp < 2; ++ksp)
        bf[tc][ksp] = *(const v2l*)(sB + brow + tc * 2048 + offp[ksp]);

#pragma unroll
    for (int tr = 0; tr < 4; ++tr) {
      const v2l a0 = *(const v2l*)(sA + arow + tr * 2048 + offp[0]);
      const v2l a1 = *(const v2l*)(sA + arow + tr * 2048 + offp[1]);
      const v4f s4 = *(const v4f*)(scb + scoff + tr * 16) * wsk;
#pragma unroll
      for (int tc = 0; tc < 4; ++tc) {
        v4f p = __builtin_amdgcn_mfma_f32_16x16x32_fp8_fp8(a0.x, bf[tc][0].x, zf, 0, 0, 0);
        p = __builtin_amdgcn_mfma_f32_16x16x32_fp8_fp8(a0.y, bf[tc][0].y, p, 0, 0, 0);
        p = __builtin_amdgcn_mfma_f32_16x16x32_fp8_fp8(a1.x, bf[tc][1].x, p, 0, 0, 0);
        p = __builtin_amdgcn_mfma_f32_16x16x32_fp8_fp8(a1.y, bf[tc][1].y, p, 0, 0, 0);
        acc[tr][tc] += p * s4;
      }
    }
    __syncthreads();
  }

  // epilogue: add residual (relu(x) for layer 0)
  const int mB = m0 + wm * 64 + quad * 4;
  const int nB = n0 + wn * 64 + l16;
#pragma unroll
  for (int tr = 0; tr < 4; ++tr) {
#pragma unroll
    for (int r = 0; r < 4; ++r) {
      const size_t rowOff = (size_t)(mB + tr * 16 + r) * H;
#pragma unroll
      for (int tc = 0; tc < 4; ++tc) {
        const size_t idx = rowOff + nB + tc * 16;
        float rv = resid[idx];
        if (relu) rv = fmaxf(rv, 0.f);
        outp[idx] = acc[tr][tc][r] + rv;
      }
    }
  }
}

extern "C" void kernel_launch(void* const* d_in, const int* in_sizes, int n_in,
                              void* d_out, int out_size, void* d_ws, size_t ws_size,
                              hipStream_t stream) {
  const float* x   = (const float*)d_in[0];
  const float* w0  = (const float*)d_in[1];
  const float* ws0 = (const float*)d_in[2];
  const float* w1  = (const float*)d_in[3];
  const float* ws1 = (const float*)d_in[4];
  const float* w2  = (const float*)d_in[5];
  const float* ws2 = (const float*)d_in[6];
  const float* nw0 = (const float*)d_in[7];
  const float* nw1 = (const float*)d_in[8];
  const float* nw2 = (const float*)d_in[9];
  const float* nw3 = (const float*)d_in[10];
  float* R = (float*)d_out;  // residual lives in d_out (in-place)

  uint8_t* base = (uint8_t*)d_ws;
  uint8_t* wq0 = base;
  uint8_t* wq1 = base + ((size_t)16 << 20);
  uint8_t* wq2 = base + ((size_t)32 << 20);
  uint8_t* qa  = base + ((size_t)48 << 20);
  float* sa    = (float*)(base + ((size_t)64 << 20));  // sxT[32][4096]

  conv_w_kernel<<<dim3(64, 32, 3), 256, 0, stream>>>(w0, w1, w2, wq0, wq1, wq2);

  quant_kernel<<<4096, 256, 0, stream>>>(x, nw0, qa, sa, 1);
  gemm_kernel<<<dim3(32, 32), 256, 0, stream>>>(qa, sa, wq0, ws0, x, R, 1);

  quant_kernel<<<4096, 256, 0, stream>>>(R, nw1, qa, sa, 0);
  gemm_kernel<<<dim3(32, 32), 256, 0, stream>>>(qa, sa, wq1, ws1, R, R, 0);

  quant_kernel<<<4096, 256, 0, stream>>>(R, nw2, qa, sa, 0);
  gemm_kernel<<<dim3(32, 32), 256, 0, stream>>>(qa, sa, wq2, ws2, R, R, 0);

  norm_kernel<<<4096, 256, 0, stream>>>(R, nw3);
}